// Round 7
// baseline (146.924 us; speedup 1.0000x reference)
//
#include <hip/hip_runtime.h>
#include <hip/hip_bf16.h>

#define NB 64
#define S_ 1024
#define D_ 128

typedef __attribute__((ext_vector_type(8))) short bf16x8;
typedef __attribute__((ext_vector_type(4))) float f32x4;
typedef __attribute__((ext_vector_type(4))) unsigned int u32x4;

// Fragment-tiled layout: operands stored as 16-row x 32-k panels of 1KB,
// element (r,k) at short-offset (((k>>3)&3)*16 + (r&15))*8 + (k&7) ==
// lane*8 + j in MFMA A/B fragment order -> a wave fragment load/store is
// base + lane*16B: one coalesced 1KB transaction.

__device__ __forceinline__ unsigned short f2bf(float f) {
  __hip_bfloat16 h = __float2bfloat16(f);
  return __builtin_bit_cast(unsigned short, h);
}

__device__ __forceinline__ void async_copy16(const void* g, void* l) {
  __builtin_amdgcn_global_load_lds(
      (const __attribute__((address_space(1))) unsigned int*)g,
      (__attribute__((address_space(3))) unsigned int*)l, 16, 0, 0);
}

// Device-scope (MALL write-through) 16B store: publishes producer data so
// consumers on ANY XCD see it after the paired atomic flag — correctness does
// not depend on blockIdx->XCD mapping (Guideline 16). sc1 = device scope.
__device__ __forceinline__ void store16_dev(void* p, bf16x8 v) {
  u32x4 d = __builtin_bit_cast(u32x4, v);
  asm volatile("global_store_dwordx4 %0, %1, off sc1" ::"v"(p), "v"(d)
               : "memory");
}

// Bounded spin until (*p & need) == need (relaxed agent atomic loads, coherent
// at MALL — R5/R6-proven protocol; worst case ~50ms then loud failure).
__device__ __forceinline__ void spin_mask(unsigned* p, unsigned need) {
  if (threadIdx.x == 0) {
    int guard = 0;
    while ((__hip_atomic_load(p, __ATOMIC_RELAXED, __HIP_MEMORY_SCOPE_AGENT) &
            need) != need) {
      __builtin_amdgcn_s_sleep(4);
      if (++guard > 400000) break;
    }
  }
  __syncthreads();
  asm volatile("" ::: "memory");
}

__device__ __forceinline__ void spin_cnt(unsigned* p, unsigned need) {
  if (threadIdx.x == 0) {
    int guard = 0;
    while (__hip_atomic_load(p, __ATOMIC_RELAXED, __HIP_MEMORY_SCOPE_AGENT) <
           need) {
      __builtin_amdgcn_s_sleep(4);
      if (++guard > 400000) break;
    }
  }
  __syncthreads();
  asm volatile("" ::: "memory");
}

// Drain own stores to coherence point, then one flag-set per block.
__device__ __forceinline__ void publish_bit(unsigned* p, unsigned bit) {
  asm volatile("s_waitcnt vmcnt(0)" ::: "memory");
  __syncthreads();
  if (threadIdx.x == 0)
    __hip_atomic_fetch_or(p, bit, __ATOMIC_RELAXED, __HIP_MEMORY_SCOPE_AGENT);
}

// Zero the 8KB stats/flag region (ws is poisoned between iterations).
__global__ __launch_bounds__(256) void init_stats(unsigned* __restrict__ c) {
#pragma unroll
  for (int i = 0; i < 8; ++i) c[threadIdx.x + i * 256] = 0u;
}

// ------------- causal batched GEMM phase: LDS-staged A, prefetched B --------
// BM=64 (t), BN=128 (d); wave owns 64m x 32n. A staged per 256-k panel into
// LDS via global_load_lds (gated to needed chunks), read as ds_read_b128.
// B: direct global->VGPR, 1KB coalesced, depth-4 rolling prefetch.
template <bool HSWISH>
__device__ __forceinline__ void gemm_phase(
    unsigned short* ldsA, const int b, const int mt,
    const unsigned short* __restrict__ Af, const unsigned short* __restrict__ Bf,
    unsigned short* __restrict__ Uf, const float* __restrict__ Xres,
    float* __restrict__ Out) {
  const int t = threadIdx.x;
  const int wave = t >> 6, lane = t & 63;
  const int quad = lane >> 4, l16 = lane & 15;
  const int row0 = mt * 64;

  const int cend = 2 * (mt + 1);       // active 32-k chunks (even, 2..32)
  const int npan = (cend + 7) >> 3;    // 256-k panels

  const unsigned short* Ab = Af + (size_t)mt * 4 * 32 * 512;
  const unsigned short* Bb = Bf + (size_t)b * (D_ * S_);

  f32x4 acc[4][2] = {};
  bf16x8 Bp[4][2];
#pragma unroll
  for (int g = 0; g < 4; ++g) {
    const int gg = (g < cend) ? g : 0;
#pragma unroll
    for (int jj = 0; jj < 2; ++jj)
      Bp[g][jj] = *(const bf16x8*)(Bb + ((size_t)(wave * 2 + jj) * 32 + gg) * 512 + lane * 8);
  }

  for (int p = 0; p < npan; ++p) {
    if (p) __syncthreads();            // protect LDS from prior-panel readers
    const int rem = cend - p * 8;      // chunks actually needed this panel
#pragma unroll
    for (int jc = 0; jc < 8; ++jc) {   // stage A panels [mt*4+iw][p*8+cc]
      const int flat16 = jc * 256 + t; // 16B units
      const int iw = flat16 >> 9;
      const int cc = (flat16 >> 6) & 7;
      const int li = flat16 & 63;
      if (cc < rem)                    // wave-uniform gate (flat16>>6 uniform)
        async_copy16(Ab + ((size_t)iw * 32 + p * 8 + cc) * 512 + li * 8,
                     ldsA + flat16 * 8);
    }
    __syncthreads();                   // drains vmcnt; A panel ready
#pragma unroll
    for (int c = 0; c < 8; ++c) {
      const int g = p * 8 + c;
      if (g < cend) {
        bf16x8 af[4];
#pragma unroll
        for (int i = 0; i < 4; ++i)
          af[i] = *(const bf16x8*)(ldsA + i * 4096 + c * 512 + lane * 8);
        __builtin_amdgcn_s_setprio(1);
#pragma unroll
        for (int i = 0; i < 4; ++i)
#pragma unroll
          for (int jj = 0; jj < 2; ++jj)
            acc[i][jj] = __builtin_amdgcn_mfma_f32_16x16x32_bf16(
                af[i], Bp[c & 3][jj], acc[i][jj], 0, 0, 0);
        __builtin_amdgcn_s_setprio(0);
        const int gn = (g + 4 < cend) ? (g + 4) : 0;
#pragma unroll
        for (int jj = 0; jj < 2; ++jj)
          Bp[c & 3][jj] = *(const bf16x8*)(
              Bb + ((size_t)(wave * 2 + jj) * 32 + gn) * 512 + lane * 8);
      }
    }
  }

  if (HSWISH) {
    __syncthreads();                   // done reading ldsA; reuse for transpose
    unsigned short* ldsT = ldsA;       // [d][t 64 + 8 pad]
#pragma unroll
    for (int i = 0; i < 4; ++i)
#pragma unroll
      for (int jj = 0; jj < 2; ++jj) {
        ushort4 pk;
        float v0 = acc[i][jj][0], v1 = acc[i][jj][1], v2 = acc[i][jj][2], v3 = acc[i][jj][3];
        pk.x = f2bf(v0 * fminf(fmaxf(v0 + 3.f, 0.f), 6.f) * (1.f / 6.f));
        pk.y = f2bf(v1 * fminf(fmaxf(v1 + 3.f, 0.f), 6.f) * (1.f / 6.f));
        pk.z = f2bf(v2 * fminf(fmaxf(v2 + 3.f, 0.f), 6.f) * (1.f / 6.f));
        pk.w = f2bf(v3 * fminf(fmaxf(v3 + 3.f, 0.f), 6.f) * (1.f / 6.f));
        const int n = wave * 32 + jj * 16 + l16;    // d
        const int m0 = i * 16 + quad * 4;           // t within 64-tile
        *(ushort4*)(ldsT + n * 72 + m0) = pk;
      }
    __syncthreads();
    unsigned short* gU = Uf + (size_t)b * (D_ * S_);
#pragma unroll
    for (int ff = 0; ff < 4; ++ff) {
      const int f = wave * 4 + ff;
      const int p2 = f >> 1, cl = f & 1;
      const int d = p2 * 16 + l16;
      const int tb = cl * 32 + quad * 8;
      bf16x8 v = *(const bf16x8*)(ldsT + d * 72 + tb);
      store16_dev(gU + ((size_t)p2 * 32 + mt * 2 + cl) * 512 + lane * 8, v);
    }
  } else {
    float* gO = Out + (size_t)b * S_ * D_;
    const float* gX = Xres + (size_t)b * S_ * D_;
#pragma unroll
    for (int i = 0; i < 4; ++i) {
      const int mrow0 = row0 + i * 16 + quad * 4;
#pragma unroll
      for (int jj = 0; jj < 2; ++jj) {
        const int col = wave * 32 + jj * 16 + l16;
#pragma unroll
        for (int r = 0; r < 4; ++r) {
          const int addr = (mrow0 + r) * D_ + col;
          gO[addr] = gX[addr] + acc[i][jj][r];
        }
      }
    }
  }
}

// ---- mega: stats(+x in regs) | W-pack | norm | gemm1 | gemm2 ---------------
// Block (b,mt): reads its x-tile ONCE into registers (stats partials from the
// same values) -> atomicAdd partials + cnt -> W-pack one 1KB fragment-chunk
// per wave (sc1 stores; hides the stats wait) -> wcnt bump -> stats wait ->
// normalize FROM REGISTERS (no x re-read) -> LDS transpose -> hTf sc1 ->
// publish h-bit mt. gemm1 waits wcnt==1024 + h-bits 0..mt, publishes u-bit.
// gemm2 runs tile mt2=15-mt (uniform 34 chunk-iters/block -> placement-robust
// balance), waits u-bits 0..mt2. All sync via MALL-coherent atomics; all
// cross-block data via sc1 write-through (no L2 wb/inv anywhere).
__global__ __launch_bounds__(256, 4) void mega_kernel(
    const float* __restrict__ x, const float* __restrict__ ln_w,
    const float* __restrict__ ln_b, const float* __restrict__ W1,
    const float* __restrict__ W2, float* __restrict__ stats,
    unsigned short* __restrict__ W1f, unsigned short* __restrict__ W2f,
    unsigned short* __restrict__ hTf, unsigned short* __restrict__ uTf,
    float* __restrict__ out) {
  __shared__ __align__(16) unsigned short smem[16384];   // 32 KB, all phases

  const int bi = blockIdx.x;           // 0..1023
  const int xcd = bi & 7;              // perf heuristic only (L2 locality)
  const int slot = bi >> 3;
  const int b = xcd * 8 + (slot & 7);
  const int j = slot >> 3;
  const int mt = (j < 8) ? j : (j ^ 3);

  const int t = threadIdx.x;
  const int wave = t >> 6, lane = t & 63;
  const int quad = lane >> 4, l16 = lane & 15;

  float* sb = stats + (size_t)b * 32;  // 128B/batch slot
  unsigned* cntp = (unsigned*)sb + 2;
  unsigned* hmp = (unsigned*)sb + 4;
  unsigned* ump = (unsigned*)sb + 6;
  unsigned* wcnt = (unsigned*)stats + 16;  // global W-pack counter (slot b=0)

  float2* w4 = (float2*)(smem + 8448); // tails after 64*132-short norm buffer
  float* mr = (float*)(smem + 8464);

  // ---------- phase A: x-tile -> registers + partial stats ------------------
  const float4* xb = (const float4*)(x + ((size_t)b * S_ + mt * 64) * D_);
  float4 xv[8];
  {
    float s = 0.f, q = 0.f;
#pragma unroll
    for (int i = 0; i < 8; ++i) {
      float4 v = xb[i * 256 + t];
      xv[i] = v;
      s += v.x + v.y + v.z + v.w;
      q += v.x * v.x + v.y * v.y + v.z * v.z + v.w * v.w;
    }
#pragma unroll
    for (int o = 32; o > 0; o >>= 1) {
      s += __shfl_down(s, o, 64);
      q += __shfl_down(q, o, 64);
    }
    if (lane == 0) w4[wave] = make_float2(s, q);
  }
  __syncthreads();
  if (t == 0) {
    float ss = 0.f, qq = 0.f;
#pragma unroll
    for (int i = 0; i < 4; ++i) { ss += w4[i].x; qq += w4[i].y; }
    float o1 = __hip_atomic_fetch_add(sb + 0, ss, __ATOMIC_RELAXED,
                                      __HIP_MEMORY_SCOPE_AGENT);
    float o2 = __hip_atomic_fetch_add(sb + 1, qq, __ATOMIC_RELAXED,
                                      __HIP_MEMORY_SCOPE_AGENT);
    asm volatile("" ::"v"(o1), "v"(o2));  // adds complete before cnt bump
    __hip_atomic_fetch_add(cntp, 1u, __ATOMIC_RELAXED,
                           __HIP_MEMORY_SCOPE_AGENT);
  }

  // ---------- W-pack (one 1KB fragment-chunk per wave; hides stats wait) ----
  {
    const int u = bi * 4 + wave;       // 0..4095 fragment-chunks
    const int f = u & 2047;
    const int p = f >> 5, c = f & 31;
    const int r = p * 16 + l16;
    const int k0 = c * 32 + quad * 8;
    const float* wsrc = ((u >> 11) ? W2 : W1) + (size_t)r * 1024 + k0;
    float4 a0 = ((const float4*)wsrc)[0];
    float4 a1 = ((const float4*)wsrc)[1];
    float av[8] = {a0.x, a0.y, a0.z, a0.w, a1.x, a1.y, a1.z, a1.w};
    bf16x8 o;
#pragma unroll
    for (int jj = 0; jj < 8; ++jj)
      o[jj] = (short)f2bf((k0 + jj <= r) ? av[jj] : 0.f);
    unsigned short* dstp = ((u >> 11) ? W2f : W1f) +
                           ((size_t)p * 32 + c) * 512 + lane * 8;
    store16_dev(dstp, o);              // consumed cross-XCD -> device scope
  }
  asm volatile("s_waitcnt vmcnt(0)" ::: "memory");
  __syncthreads();
  if (t == 0) {
    __hip_atomic_fetch_add(wcnt, 1u, __ATOMIC_RELAXED,
                           __HIP_MEMORY_SCOPE_AGENT);
    int guard = 0;                     // wait all 16 stats partials of b
    while (__hip_atomic_load(cntp, __ATOMIC_RELAXED,
                             __HIP_MEMORY_SCOPE_AGENT) < 16u) {
      __builtin_amdgcn_s_sleep(4);
      if (++guard > 400000) break;
    }
    float s1 = __hip_atomic_load(sb + 0, __ATOMIC_RELAXED,
                                 __HIP_MEMORY_SCOPE_AGENT);
    float s2 = __hip_atomic_load(sb + 1, __ATOMIC_RELAXED,
                                 __HIP_MEMORY_SCOPE_AGENT);
    const float inv = 1.0f / (S_ * D_);
    const float mu = s1 * inv;
    mr[0] = mu;
    mr[1] = rsqrtf(s2 * inv - mu * mu + 1e-5f);
  }
  __syncthreads();
  const float mu = mr[0];
  const float rs = mr[1];

  // ---------- normalize from registers + LDS [s][d+4pad] transpose ----------
  {
    unsigned short* lds = smem;
    const float4* wb = (const float4*)(ln_w + (size_t)(mt * 64) * D_);
    const float4* bv4 = (const float4*)(ln_b + (size_t)(mt * 64) * D_);
#pragma unroll
    for (int r = 0; r < 8; ++r) {
      const int f = r * 256 + t;
      const int srow = f >> 5;
      const int c4 = f & 31;
      float4 wv = wb[f];
      float4 bvv = bv4[f];
      ushort4 o;
      o.x = f2bf((xv[r].x - mu) * rs * wv.x + bvv.x);
      o.y = f2bf((xv[r].y - mu) * rs * wv.y + bvv.y);
      o.z = f2bf((xv[r].z - mu) * rs * wv.z + bvv.z);
      o.w = f2bf((xv[r].w - mu) * rs * wv.w + bvv.w);
      *(ushort4*)(lds + srow * 132 + c4 * 4) = o;
    }
    __syncthreads();
    unsigned short* outp = hTf + (size_t)b * (D_ * S_);
    const int cg0 = mt * 2;
#pragma unroll
    for (int ff = 0; ff < 4; ++ff) {
      const int f = wave * 4 + ff;     // 16 fragments per block
      const int p = f >> 1, cl = f & 1;
      const int d = p * 16 + l16;
      const int sbase = cl * 32 + quad * 8;
      bf16x8 v;
#pragma unroll
      for (int jj = 0; jj < 8; ++jj)
        v[jj] = (short)lds[(sbase + jj) * 132 + d];
      store16_dev(outp + ((size_t)p * 32 + cg0 + cl) * 512 + lane * 8, v);
    }
  }
  publish_bit(hmp, 1u << mt);

  // ---------- gemm1: u = hardswish(W1c @ h) at tile mt ----------------------
  spin_cnt(wcnt, 1024);                // W1f/W2f fully packed
  spin_mask(hmp, (2u << mt) - 1);      // h chunks 0..cend-1 published
  gemm_phase<true>(smem, b, mt, W1f, hTf, uTf, nullptr, nullptr);
  publish_bit(ump, 1u << mt);

  // ---------- gemm2: out = x + W2c @ u at tile mt2=15-mt (uniform load) -----
  const int mt2 = 15 - mt;
  spin_mask(ump, (2u << mt2) - 1);     // u chunks 0..cend2-1 published
  gemm_phase<false>(smem, b, mt2, W2f, uTf, nullptr, x, out);
}

extern "C" void kernel_launch(void* const* d_in, const int* in_sizes, int n_in,
                              void* d_out, int out_size, void* d_ws, size_t ws_size,
                              hipStream_t stream) {
  const float* x = (const float*)d_in[0];
  const float* ln_w = (const float*)d_in[1];
  const float* ln_b = (const float*)d_in[2];
  const float* W1 = (const float*)d_in[3];
  const float* W2 = (const float*)d_in[4];
  float* out = (float*)d_out;

  char* ws = (char*)d_ws;
  float* stats = (float*)ws;                                 // 8 KiB (64x128B)
  unsigned short* W1f = (unsigned short*)(ws + 16384);       // 2 MiB
  unsigned short* W2f = W1f + (size_t)S_ * S_;               // 2 MiB
  unsigned short* hTf = W2f + (size_t)S_ * S_;               // 16 MiB
  unsigned short* uTf = hTf + (size_t)NB * D_ * S_;          // 16 MiB

  init_stats<<<1, 256, 0, stream>>>((unsigned*)stats);
  mega_kernel<<<1024, 256, 0, stream>>>(x, ln_w, ln_b, W1, W2, stats,
                                        W1f, W2f, hTf, uTf, out);
}

// Round 8
// 133.886 us; speedup vs baseline: 1.0974x; 1.0974x over previous
//
#include <hip/hip_runtime.h>
#include <hip/hip_bf16.h>

#define NB 64
#define S_ 1024
#define D_ 128

typedef __attribute__((ext_vector_type(8))) short bf16x8;
typedef __attribute__((ext_vector_type(4))) float f32x4;
typedef __attribute__((ext_vector_type(4))) unsigned int u32x4;

// Fragment-tiled layout: operands stored as 16-row x 32-k panels of 1KB,
// element (r,k) at short-offset (((k>>3)&3)*16 + (r&15))*8 + (k&7) ==
// lane*8 + j in MFMA A/B fragment order -> a wave fragment load/store is
// base + lane*16B: one coalesced 1KB transaction.

__device__ __forceinline__ unsigned short f2bf(float f) {
  __hip_bfloat16 h = __float2bfloat16(f);
  return __builtin_bit_cast(unsigned short, h);
}

__device__ __forceinline__ void async_copy16(const void* g, void* l) {
  __builtin_amdgcn_global_load_lds(
      (const __attribute__((address_space(1))) unsigned int*)g,
      (__attribute__((address_space(3))) unsigned int*)l, 16, 0, 0);
}

// Device-scope (MALL write-through) 16B store: publishes producer data so
// consumers on ANY XCD see it after the paired atomic flag — correctness does
// not depend on blockIdx->XCD mapping (Guideline 16). sc1 = device scope.
__device__ __forceinline__ void store16_dev(void* p, bf16x8 v) {
  u32x4 d = __builtin_bit_cast(u32x4, v);
  asm volatile("global_store_dwordx4 %0, %1, off sc1" ::"v"(p), "v"(d)
               : "memory");
}

// Bounded spin until (*p & need) == need (relaxed agent atomic loads, coherent
// at MALL — R5/R6-proven protocol; worst case ~tens of ms then loud failure).
// Ends with a block barrier, so it also serves as the LDS-protection barrier.
__device__ __forceinline__ void spin_mask(unsigned* p, unsigned need) {
  if (threadIdx.x == 0) {
    int guard = 0;
    while ((__hip_atomic_load(p, __ATOMIC_RELAXED, __HIP_MEMORY_SCOPE_AGENT) &
            need) != need) {
      __builtin_amdgcn_s_sleep(1);
      if (++guard > 2000000) break;
    }
  }
  __syncthreads();
  asm volatile("" ::: "memory");
}

// Drain own stores to coherence point, then one flag-set per block.
__device__ __forceinline__ void publish_bit(unsigned* p, unsigned bit) {
  asm volatile("s_waitcnt vmcnt(0)" ::: "memory");
  __syncthreads();
  if (threadIdx.x == 0)
    __hip_atomic_fetch_or(p, bit, __ATOMIC_RELAXED, __HIP_MEMORY_SCOPE_AGENT);
}

// ---- K1: W-pack (bf16 fragment-tiled causal W1/W2) + zero the stats slots --
// Kernel boundary publishes W1f/W2f to the mega kernel (end-of-kernel
// writeback + dispatch acquire — the mechanism R5/R6's passing runs validate).
__global__ __launch_bounds__(256) void wpack_kernel(
    const float* __restrict__ W1, const float* __restrict__ W2,
    unsigned short* __restrict__ W1f, unsigned short* __restrict__ W2f,
    unsigned* __restrict__ stats) {
  const int blk = blockIdx.x;          // 0..511
  const int t = threadIdx.x;
  const int wave = t >> 6, lane = t & 63;
  const int quad = lane >> 4, l16 = lane & 15;
  if (blk == 0) {                      // zero 64 x 128B stats/flag slots
#pragma unroll
    for (int i = 0; i < 8; ++i) stats[t + i * 256] = 0u;
  }
#pragma unroll
  for (int rep = 0; rep < 2; ++rep) {
    const int u = blk * 8 + wave * 2 + rep;   // 0..4095 fragment-chunks
    const int f = u & 2047;
    const int p = f >> 5, c = f & 31;
    const int r = p * 16 + l16;
    const int k0 = c * 32 + quad * 8;
    const float* wsrc = ((u >> 11) ? W2 : W1) + (size_t)r * 1024 + k0;
    float4 a0 = ((const float4*)wsrc)[0];
    float4 a1 = ((const float4*)wsrc)[1];
    float av[8] = {a0.x, a0.y, a0.z, a0.w, a1.x, a1.y, a1.z, a1.w};
    bf16x8 o;
#pragma unroll
    for (int jj = 0; jj < 8; ++jj)
      o[jj] = (short)f2bf((k0 + jj <= r) ? av[jj] : 0.f);
    unsigned short* dstp = ((u >> 11) ? W2f : W1f) +
                           ((size_t)p * 32 + c) * 512 + lane * 8;
    *(bf16x8*)dstp = o;
  }
}

// ------------- causal batched GEMM phase: LDS-staged A, prefetched B --------
// BM=64 (t), BN=128 (d); wave owns 64m x 32n. A staged per 256-k panel into
// LDS via global_load_lds (gated to needed chunks), read as ds_read_b128.
// B: direct global->VGPR, 1KB coalesced, depth-4 rolling prefetch.
// PROGRESSIVE dependency waits: chunk c needs producer bit c>>1; each panel
// top spins only on bits covering chunks through p*8+11 (panel + 4-chunk
// B-prefetch lookahead, so no B load ever targets unpublished data). Big
// tiles start as soon as the first producers publish instead of after ALL.
template <bool HSWISH>
__device__ __forceinline__ void gemm_phase(
    unsigned short* ldsA, const int b, const int mt, unsigned* flags,
    const unsigned short* __restrict__ Af, const unsigned short* __restrict__ Bf,
    unsigned short* __restrict__ Uf, const float* __restrict__ Xres,
    float* __restrict__ Out) {
  const int t = threadIdx.x;
  const int wave = t >> 6, lane = t & 63;
  const int quad = lane >> 4, l16 = lane & 15;
  const int row0 = mt * 64;

  const int cend = 2 * (mt + 1);       // active 32-k chunks (even, 2..32)
  const int npan = (cend + 7) >> 3;    // 256-k panels

  const unsigned short* Ab = Af + (size_t)mt * 4 * 32 * 512;
  const unsigned short* Bb = Bf + (size_t)b * (D_ * S_);

  // wait for producers of chunks 0..min(11,cend-1) (initial prefetch + pan 0)
  {
    const int C = (cend - 1 < 11) ? (cend - 1) : 11;
    spin_mask(flags, (2u << (C >> 1)) - 1u);
  }

  f32x4 acc[4][2] = {};
  bf16x8 Bp[4][2];
#pragma unroll
  for (int g = 0; g < 4; ++g) {
    const int gg = (g < cend) ? g : 0;
#pragma unroll
    for (int jj = 0; jj < 2; ++jj)
      Bp[g][jj] = *(const bf16x8*)(Bb + ((size_t)(wave * 2 + jj) * 32 + gg) * 512 + lane * 8);
  }

  for (int p = 0; p < npan; ++p) {
    if (p) {                           // barrier (LDS protect) + next-dep wait
      const int C = (cend - 1 < p * 8 + 11) ? (cend - 1) : (p * 8 + 11);
      spin_mask(flags, (2u << (C >> 1)) - 1u);
    }
    const int rem = cend - p * 8;      // chunks actually needed this panel
#pragma unroll
    for (int jc = 0; jc < 8; ++jc) {   // stage A panels [mt*4+iw][p*8+cc]
      const int flat16 = jc * 256 + t; // 16B units
      const int iw = flat16 >> 9;
      const int cc = (flat16 >> 6) & 7;
      const int li = flat16 & 63;
      if (cc < rem)                    // wave-uniform gate (flat16>>6 uniform)
        async_copy16(Ab + ((size_t)iw * 32 + p * 8 + cc) * 512 + li * 8,
                     ldsA + flat16 * 8);
    }
    __syncthreads();                   // drains vmcnt; A panel ready
#pragma unroll
    for (int c = 0; c < 8; ++c) {
      const int g = p * 8 + c;
      if (g < cend) {
        bf16x8 af[4];
#pragma unroll
        for (int i = 0; i < 4; ++i)
          af[i] = *(const bf16x8*)(ldsA + i * 4096 + c * 512 + lane * 8);
        __builtin_amdgcn_s_setprio(1);
#pragma unroll
        for (int i = 0; i < 4; ++i)
#pragma unroll
          for (int jj = 0; jj < 2; ++jj)
            acc[i][jj] = __builtin_amdgcn_mfma_f32_16x16x32_bf16(
                af[i], Bp[c & 3][jj], acc[i][jj], 0, 0, 0);
        __builtin_amdgcn_s_setprio(0);
        const int gn = (g + 4 < cend) ? (g + 4) : 0;
#pragma unroll
        for (int jj = 0; jj < 2; ++jj)
          Bp[c & 3][jj] = *(const bf16x8*)(
              Bb + ((size_t)(wave * 2 + jj) * 32 + gn) * 512 + lane * 8);
      }
    }
  }

  if (HSWISH) {
    __syncthreads();                   // done reading ldsA; reuse for transpose
    unsigned short* ldsT = ldsA;       // [d][t 64 + 8 pad]
#pragma unroll
    for (int i = 0; i < 4; ++i)
#pragma unroll
      for (int jj = 0; jj < 2; ++jj) {
        ushort4 pk;
        float v0 = acc[i][jj][0], v1 = acc[i][jj][1], v2 = acc[i][jj][2], v3 = acc[i][jj][3];
        pk.x = f2bf(v0 * fminf(fmaxf(v0 + 3.f, 0.f), 6.f) * (1.f / 6.f));
        pk.y = f2bf(v1 * fminf(fmaxf(v1 + 3.f, 0.f), 6.f) * (1.f / 6.f));
        pk.z = f2bf(v2 * fminf(fmaxf(v2 + 3.f, 0.f), 6.f) * (1.f / 6.f));
        pk.w = f2bf(v3 * fminf(fmaxf(v3 + 3.f, 0.f), 6.f) * (1.f / 6.f));
        const int n = wave * 32 + jj * 16 + l16;    // d
        const int m0 = i * 16 + quad * 4;           // t within 64-tile
        *(ushort4*)(ldsT + n * 72 + m0) = pk;
      }
    __syncthreads();
    unsigned short* gU = Uf + (size_t)b * (D_ * S_);
#pragma unroll
    for (int ff = 0; ff < 4; ++ff) {
      const int f = wave * 4 + ff;
      const int p2 = f >> 1, cl = f & 1;
      const int d = p2 * 16 + l16;
      const int tb = cl * 32 + quad * 8;
      bf16x8 v = *(const bf16x8*)(ldsT + d * 72 + tb);
      store16_dev(gU + ((size_t)p2 * 32 + mt * 2 + cl) * 512 + lane * 8, v);
    }
  } else {
    float* gO = Out + (size_t)b * S_ * D_;
    const float* gX = Xres + (size_t)b * S_ * D_;
#pragma unroll
    for (int i = 0; i < 4; ++i) {
      const int mrow0 = row0 + i * 16 + quad * 4;
#pragma unroll
      for (int jj = 0; jj < 2; ++jj) {
        const int col = wave * 32 + jj * 16 + l16;
#pragma unroll
        for (int r = 0; r < 4; ++r) {
          const int addr = (mrow0 + r) * D_ + col;
          gO[addr] = gX[addr] + acc[i][jj][r];
        }
      }
    }
  }
}

// ---- K2 mega: stats+norm -> gemm1 -> gemm2, chained by per-batch atomics ---
// Block (b,mt): stats over x s-tile mt -> atomicAdd partials + cnt; spin
// cnt[b]==16; normalize own tile -> hTf chunks {2mt,2mt+1} via sc1 stores ->
// publish h-bit mt. gemm1/gemm2 use PROGRESSIVE per-panel waits on the h/u
// bitmasks (see gemm_phase). DAG acyclic, all 1024 blocks resident (4/CU x
// 256), per-CU work balanced (each CU's 4 mts sum to 68 chunk-iters/phase).
__global__ __launch_bounds__(256, 4) void mega_kernel(
    const float* __restrict__ x, const float* __restrict__ ln_w,
    const float* __restrict__ ln_b, const unsigned short* __restrict__ W1f,
    const unsigned short* __restrict__ W2f, float* __restrict__ stats,
    unsigned short* __restrict__ hTf, unsigned short* __restrict__ uTf,
    float* __restrict__ out) {
  __shared__ __align__(16) unsigned short smem[16384];   // 32 KB, all phases

  const int bi = blockIdx.x;           // 0..1023
  const int xcd = bi & 7;              // perf heuristic only (L2 locality)
  const int slot = bi >> 3;
  const int b = xcd * 8 + (slot & 7);
  const int j = slot >> 3;
  const int mt = (j < 8) ? j : (j ^ 3);

  const int t = threadIdx.x;
  const int wave = t >> 6, lane = t & 63;
  const int quad = lane >> 4, l16 = lane & 15;

  float* sb = stats + (size_t)b * 32;  // 128B/batch slot
  unsigned* cntp = (unsigned*)sb + 2;
  unsigned* hmp = (unsigned*)sb + 4;
  unsigned* ump = (unsigned*)sb + 6;

  float2* w4 = (float2*)(smem + 8448); // tails after 64*132-short norm buffer
  float* mr = (float*)(smem + 8464);

  // ---------- phase A: partial stats (own s-tile = rows 64mt..64mt+63) ------
  const float4* xb = (const float4*)(x + ((size_t)b * S_ + mt * 64) * D_);
  {
    float s = 0.f, q = 0.f;
#pragma unroll
    for (int i = 0; i < 8; ++i) {
      float4 v = xb[i * 256 + t];
      s += v.x + v.y + v.z + v.w;
      q += v.x * v.x + v.y * v.y + v.z * v.z + v.w * v.w;
    }
#pragma unroll
    for (int o = 32; o > 0; o >>= 1) {
      s += __shfl_down(s, o, 64);
      q += __shfl_down(q, o, 64);
    }
    if (lane == 0) w4[wave] = make_float2(s, q);
  }
  __syncthreads();
  if (t == 0) {
    float ss = 0.f, qq = 0.f;
#pragma unroll
    for (int i = 0; i < 4; ++i) { ss += w4[i].x; qq += w4[i].y; }
    float o1 = __hip_atomic_fetch_add(sb + 0, ss, __ATOMIC_RELAXED,
                                      __HIP_MEMORY_SCOPE_AGENT);
    float o2 = __hip_atomic_fetch_add(sb + 1, qq, __ATOMIC_RELAXED,
                                      __HIP_MEMORY_SCOPE_AGENT);
    asm volatile("" ::"v"(o1), "v"(o2));  // adds complete before cnt bump
    __hip_atomic_fetch_add(cntp, 1u, __ATOMIC_RELAXED,
                           __HIP_MEMORY_SCOPE_AGENT);
    int guard = 0;
    while (__hip_atomic_load(cntp, __ATOMIC_RELAXED,
                             __HIP_MEMORY_SCOPE_AGENT) < 16u) {
      __builtin_amdgcn_s_sleep(1);
      if (++guard > 2000000) break;
    }
    float s1 = __hip_atomic_load(sb + 0, __ATOMIC_RELAXED,
                                 __HIP_MEMORY_SCOPE_AGENT);
    float s2 = __hip_atomic_load(sb + 1, __ATOMIC_RELAXED,
                                 __HIP_MEMORY_SCOPE_AGENT);
    const float inv = 1.0f / (S_ * D_);
    const float mu = s1 * inv;
    mr[0] = mu;
    mr[1] = rsqrtf(s2 * inv - mu * mu + 1e-5f);
  }
  __syncthreads();
  const float mu = mr[0];
  const float rs = mr[1];

  // ---------- normalize (x-tile L1/L2-hot) + LDS [s][d+4pad] transpose ------
  {
    unsigned short* lds = smem;
    const float4* wb = (const float4*)(ln_w + (size_t)(mt * 64) * D_);
    const float4* bv4 = (const float4*)(ln_b + (size_t)(mt * 64) * D_);
#pragma unroll
    for (int r = 0; r < 8; ++r) {
      const int f = r * 256 + t;
      const int srow = f >> 5;
      const int c4 = f & 31;
      float4 xv = xb[f];
      float4 wv = wb[f];
      float4 bvv = bv4[f];
      ushort4 o;
      o.x = f2bf((xv.x - mu) * rs * wv.x + bvv.x);
      o.y = f2bf((xv.y - mu) * rs * wv.y + bvv.y);
      o.z = f2bf((xv.z - mu) * rs * wv.z + bvv.z);
      o.w = f2bf((xv.w - mu) * rs * wv.w + bvv.w);
      *(ushort4*)(lds + srow * 132 + c4 * 4) = o;
    }
    __syncthreads();
    unsigned short* outp = hTf + (size_t)b * (D_ * S_);
    const int cg0 = mt * 2;
#pragma unroll
    for (int ff = 0; ff < 4; ++ff) {
      const int f = wave * 4 + ff;     // 16 fragments per block
      const int p = f >> 1, cl = f & 1;
      const int d = p * 16 + l16;
      const int sbase = cl * 32 + quad * 8;
      bf16x8 v;
#pragma unroll
      for (int jj = 0; jj < 8; ++jj)
        v[jj] = (short)lds[(sbase + jj) * 132 + d];
      store16_dev(outp + ((size_t)p * 32 + cg0 + cl) * 512 + lane * 8, v);
    }
  }
  publish_bit(hmp, 1u << mt);

  // ---------- gemm1: u = hardswish(W1c @ h), progressive h-bit waits --------
  gemm_phase<true>(smem, b, mt, hmp, W1f, hTf, uTf, nullptr, nullptr);
  publish_bit(ump, 1u << mt);

  // ---------- gemm2: out = x + W2c @ u, progressive u-bit waits -------------
  gemm_phase<false>(smem, b, mt, ump, W2f, uTf, nullptr, x, out);
}

extern "C" void kernel_launch(void* const* d_in, const int* in_sizes, int n_in,
                              void* d_out, int out_size, void* d_ws, size_t ws_size,
                              hipStream_t stream) {
  const float* x = (const float*)d_in[0];
  const float* ln_w = (const float*)d_in[1];
  const float* ln_b = (const float*)d_in[2];
  const float* W1 = (const float*)d_in[3];
  const float* W2 = (const float*)d_in[4];
  float* out = (float*)d_out;

  char* ws = (char*)d_ws;
  float* stats = (float*)ws;                                 // 8 KiB (64x128B)
  unsigned short* W1f = (unsigned short*)(ws + 16384);       // 2 MiB
  unsigned short* W2f = W1f + (size_t)S_ * S_;               // 2 MiB
  unsigned short* hTf = W2f + (size_t)S_ * S_;               // 16 MiB
  unsigned short* uTf = hTf + (size_t)NB * D_ * S_;          // 16 MiB

  wpack_kernel<<<512, 256, 0, stream>>>(W1, W2, W1f, W2f, (unsigned*)stats);
  mega_kernel<<<1024, 256, 0, stream>>>(x, ln_w, ln_b, W1f, W2f, stats,
                                        hTf, uTf, out);
}

// Round 9
// 131.200 us; speedup vs baseline: 1.1199x; 1.0205x over previous
//
#include <hip/hip_runtime.h>
#include <hip/hip_bf16.h>

#define NB 64
#define S_ 1024
#define D_ 128

typedef __attribute__((ext_vector_type(8))) short bf16x8;
typedef __attribute__((ext_vector_type(4))) float f32x4;
typedef __attribute__((ext_vector_type(4))) unsigned int u32x4;

// Fragment-tiled layout: operands stored as 16-row x 32-k panels of 1KB,
// element (r,k) at short-offset (((k>>3)&3)*16 + (r&15))*8 + (k&7) ==
// lane*8 + j in MFMA A/B fragment order -> a wave fragment load/store is
// base + lane*16B: one coalesced 1KB transaction.

__device__ __forceinline__ unsigned short f2bf(float f) {
  __hip_bfloat16 h = __float2bfloat16(f);
  return __builtin_bit_cast(unsigned short, h);
}

__device__ __forceinline__ void async_copy16(const void* g, void* l) {
  __builtin_amdgcn_global_load_lds(
      (const __attribute__((address_space(1))) unsigned int*)g,
      (__attribute__((address_space(3))) unsigned int*)l, 16, 0, 0);
}

// Device-scope (MALL write-through) 16B store: publishes producer data so
// consumers on ANY XCD see it after the paired atomic flag — correctness does
// not depend on blockIdx->XCD mapping (Guideline 16). sc1 = device scope.
__device__ __forceinline__ void store16_dev(void* p, bf16x8 v) {
  u32x4 d = __builtin_bit_cast(u32x4, v);
  asm volatile("global_store_dwordx4 %0, %1, off sc1" ::"v"(p), "v"(d)
               : "memory");
}

// Bounded spin until (*p & need) == need (relaxed agent atomic loads, coherent
// at MALL — R5/R6-proven protocol; worst case ~tens of ms then loud failure).
__device__ __forceinline__ void spin_mask(unsigned* p, unsigned need) {
  if (threadIdx.x == 0) {
    int guard = 0;
    while ((__hip_atomic_load(p, __ATOMIC_RELAXED, __HIP_MEMORY_SCOPE_AGENT) &
            need) != need) {
      __builtin_amdgcn_s_sleep(1);
      if (++guard > 2000000) break;
    }
  }
  __syncthreads();
  asm volatile("" ::: "memory");
}

// Drain own stores to coherence point, then one flag-set per block.
__device__ __forceinline__ void publish_bit(unsigned* p, unsigned bit) {
  asm volatile("s_waitcnt vmcnt(0)" ::: "memory");
  __syncthreads();
  if (threadIdx.x == 0)
    __hip_atomic_fetch_or(p, bit, __ATOMIC_RELAXED, __HIP_MEMORY_SCOPE_AGENT);
}

// ---- K1: W-pack (bf16 fragment-tiled causal W1/W2) + zero the stats slots --
// Kernel boundary publishes W1f/W2f to the mega kernel (end-of-kernel
// writeback + dispatch acquire — the mechanism R5/R6's passing runs validate).
__global__ __launch_bounds__(256) void wpack_kernel(
    const float* __restrict__ W1, const float* __restrict__ W2,
    unsigned short* __restrict__ W1f, unsigned short* __restrict__ W2f,
    unsigned* __restrict__ stats) {
  const int blk = blockIdx.x;          // 0..511
  const int t = threadIdx.x;
  const int wave = t >> 6, lane = t & 63;
  const int quad = lane >> 4, l16 = lane & 15;
  if (blk == 0) {                      // zero 64 x 128B stats/flag slots
#pragma unroll
    for (int i = 0; i < 8; ++i) stats[t + i * 256] = 0u;
  }
#pragma unroll
  for (int rep = 0; rep < 2; ++rep) {
    const int u = blk * 8 + wave * 2 + rep;   // 0..4095 fragment-chunks
    const int f = u & 2047;
    const int p = f >> 5, c = f & 31;
    const int r = p * 16 + l16;
    const int k0 = c * 32 + quad * 8;
    const float* wsrc = ((u >> 11) ? W2 : W1) + (size_t)r * 1024 + k0;
    float4 a0 = ((const float4*)wsrc)[0];
    float4 a1 = ((const float4*)wsrc)[1];
    float av[8] = {a0.x, a0.y, a0.z, a0.w, a1.x, a1.y, a1.z, a1.w};
    bf16x8 o;
#pragma unroll
    for (int jj = 0; jj < 8; ++jj)
      o[jj] = (short)f2bf((k0 + jj <= r) ? av[jj] : 0.f);
    unsigned short* dstp = ((u >> 11) ? W2f : W1f) +
                           ((size_t)p * 32 + c) * 512 + lane * 8;
    *(bf16x8*)dstp = o;
  }
}

// ------------- causal batched GEMM phase: pipelined LDS A, prefetched B -----
// BM=64 (t), BN=128 (d); wave owns 64m x 32n. A is staged in 16KB
// quarter-panels (4 chunks), DOUBLE-BUFFERED in the same 32KB LDS, via
// global_load_lds with hand-counted vmcnt (T3/T4: never drain to 0 in-loop).
// Per-wave vmcnt accounting (issue order is pinned by sched_barrier(0)):
//   STAGE(q)[4/thread] ... B-refills[exactly 8/quarter] ... STAGE(q+1)[4]
//   => own STAGE(q) retired  <=>  vmcnt(12)  (last quarter: vmcnt(8)).
// Raw s_barrier (no compiler vmcnt(0) drain) syncs the waves; stage gate
// `wave < rem` is wave-uniform and only trims the LAST quarter, whose gated
// waves then have nothing to wait for. B: direct global->VGPR, 1KB coalesced,
// depth-4 rolling prefetch (refills unconditional so the count stays 8).
template <bool HSWISH>
__device__ __forceinline__ void gemm_phase(
    unsigned short* ldsA, const int b, const int mt, unsigned* flags,
    const unsigned short* __restrict__ Af, const unsigned short* __restrict__ Bf,
    unsigned short* __restrict__ Uf, const float* __restrict__ Xres,
    float* __restrict__ Out) {
  const int t = threadIdx.x;
  const int wave = t >> 6, lane = t & 63;
  const int quad = lane >> 4, l16 = lane & 15;
  const int row0 = mt * 64;

  const int cend = 2 * (mt + 1);       // active 32-k chunks (even, 2..32)
  const int nq = (cend + 3) >> 2;      // 4-chunk quarter-panels (16KB)

  const unsigned short* Ab = Af + (size_t)mt * 4 * 32 * 512;
  const unsigned short* Bb = Bf + (size_t)b * (D_ * S_);

  spin_mask(flags, (2u << mt) - 1);    // producers of chunks 0..cend-1 done

  // stage quarter q into ping-pong buffer: thread t loads A[iw=jc][c0+wave]
  // lane-slice; dest flat16*8 == iw*2048 + wave*512 + lane*8 (16B coalesced).
  auto STAGE = [&](int q) {
    unsigned short* buf = ldsA + (q & 1) * 8192;
    const int c0 = q * 4;
    if (wave < cend - c0) {            // wave-uniform gate
#pragma unroll
      for (int jc = 0; jc < 4; ++jc) {
        const int flat16 = jc * 256 + t;
        async_copy16(Ab + ((size_t)jc * 32 + c0 + wave) * 512 + lane * 8,
                     buf + flat16 * 8);
      }
    }
  };

  STAGE(0);                            // oldest 4 loads/thread
  if (nq > 1) STAGE(1);                // +4
  __builtin_amdgcn_sched_barrier(0);   // pin stage-before-B issue order

  f32x4 acc[4][2] = {};
  bf16x8 Bp[4][2];
#pragma unroll
  for (int g = 0; g < 4; ++g) {        // +8 B loads (after stages)
    const int gg = (g < cend) ? g : 0;
#pragma unroll
    for (int jj = 0; jj < 2; ++jj)
      Bp[g][jj] = *(const bf16x8*)(Bb + ((size_t)(wave * 2 + jj) * 32 + gg) * 512 + lane * 8);
  }

  for (int q = 0; q < nq; ++q) {
    if (q < nq - 1)                    // T4: counted, never 0 in-loop
      asm volatile("s_waitcnt vmcnt(12)" ::: "memory");
    else
      asm volatile("s_waitcnt vmcnt(8)" ::: "memory");
    __builtin_amdgcn_s_barrier();      // all waves' STAGE(q) LDS writes done
    __builtin_amdgcn_sched_barrier(0);
    unsigned short* buf = ldsA + (q & 1) * 8192;
#pragma unroll
    for (int c = 0; c < 4; ++c) {
      const int g = q * 4 + c;
      if (g < cend) {
        bf16x8 af[4];
#pragma unroll
        for (int i = 0; i < 4; ++i)
          af[i] = *(const bf16x8*)(buf + i * 2048 + c * 512 + lane * 8);
        __builtin_amdgcn_s_setprio(1);
#pragma unroll
        for (int i = 0; i < 4; ++i)
#pragma unroll
          for (int jj = 0; jj < 2; ++jj)
            acc[i][jj] = __builtin_amdgcn_mfma_f32_16x16x32_bf16(
                af[i], Bp[c][jj], acc[i][jj], 0, 0, 0);
        __builtin_amdgcn_s_setprio(0);
      }
      const int gn = (g + 4 < cend) ? (g + 4) : 0;  // unconditional: 8/quarter
#pragma unroll
      for (int jj = 0; jj < 2; ++jj)
        Bp[c][jj] = *(const bf16x8*)(
            Bb + ((size_t)(wave * 2 + jj) * 32 + gn) * 512 + lane * 8);
    }
    __builtin_amdgcn_sched_barrier(0); // refills stay above the barrier
    __builtin_amdgcn_s_barrier();      // all waves done reading buf
    __builtin_amdgcn_sched_barrier(0);
    if (q + 2 < nq) STAGE(q + 2);      // overwrite just-freed buffer
  }

  if (HSWISH) {
    __syncthreads();                   // done with staging; reuse LDS
    unsigned short* ldsT = ldsA;       // [d][t 64 + 8 pad]
#pragma unroll
    for (int i = 0; i < 4; ++i)
#pragma unroll
      for (int jj = 0; jj < 2; ++jj) {
        ushort4 pk;
        float v0 = acc[i][jj][0], v1 = acc[i][jj][1], v2 = acc[i][jj][2], v3 = acc[i][jj][3];
        pk.x = f2bf(v0 * fminf(fmaxf(v0 + 3.f, 0.f), 6.f) * (1.f / 6.f));
        pk.y = f2bf(v1 * fminf(fmaxf(v1 + 3.f, 0.f), 6.f) * (1.f / 6.f));
        pk.z = f2bf(v2 * fminf(fmaxf(v2 + 3.f, 0.f), 6.f) * (1.f / 6.f));
        pk.w = f2bf(v3 * fminf(fmaxf(v3 + 3.f, 0.f), 6.f) * (1.f / 6.f));
        const int n = wave * 32 + jj * 16 + l16;    // d
        const int m0 = i * 16 + quad * 4;           // t within 64-tile
        *(ushort4*)(ldsT + n * 72 + m0) = pk;
      }
    __syncthreads();
    unsigned short* gU = Uf + (size_t)b * (D_ * S_);
#pragma unroll
    for (int ff = 0; ff < 4; ++ff) {
      const int f = wave * 4 + ff;
      const int p2 = f >> 1, cl = f & 1;
      const int d = p2 * 16 + l16;
      const int tb = cl * 32 + quad * 8;
      bf16x8 v = *(const bf16x8*)(ldsT + d * 72 + tb);
      store16_dev(gU + ((size_t)p2 * 32 + mt * 2 + cl) * 512 + lane * 8, v);
    }
  } else {
    float* gO = Out + (size_t)b * S_ * D_;
    const float* gX = Xres + (size_t)b * S_ * D_;
#pragma unroll
    for (int i = 0; i < 4; ++i) {
      const int mrow0 = row0 + i * 16 + quad * 4;
#pragma unroll
      for (int jj = 0; jj < 2; ++jj) {
        const int col = wave * 32 + jj * 16 + l16;
#pragma unroll
        for (int r = 0; r < 4; ++r) {
          const int addr = (mrow0 + r) * D_ + col;
          gO[addr] = gX[addr] + acc[i][jj][r];
        }
      }
    }
  }
}

// ---- K2 mega: stats+norm -> gemm1 -> gemm2, chained by per-batch atomics ---
// Block (b,mt): stats over x s-tile mt -> atomicAdd partials + cnt; spin
// cnt[b]==16; normalize own tile -> hTf chunks {2mt,2mt+1} via sc1 stores ->
// publish h-bit mt. gemm1 waits h-bits 0..mt, publishes u-bit; gemm2 waits
// u-bits 0..mt. DAG acyclic, all 1024 blocks resident (4/CU x 256), per-CU
// work balanced (each CU's 4 mts sum to 68 chunk-iters/phase).
__global__ __launch_bounds__(256, 4) void mega_kernel(
    const float* __restrict__ x, const float* __restrict__ ln_w,
    const float* __restrict__ ln_b, const unsigned short* __restrict__ W1f,
    const unsigned short* __restrict__ W2f, float* __restrict__ stats,
    unsigned short* __restrict__ hTf, unsigned short* __restrict__ uTf,
    float* __restrict__ out) {
  __shared__ __align__(16) unsigned short smem[16384];   // 32 KB, all phases

  const int bi = blockIdx.x;           // 0..1023
  const int xcd = bi & 7;              // perf heuristic only (L2 locality)
  const int slot = bi >> 3;
  const int b = xcd * 8 + (slot & 7);
  const int j = slot >> 3;
  const int mt = (j < 8) ? j : (j ^ 3);

  const int t = threadIdx.x;
  const int wave = t >> 6, lane = t & 63;
  const int quad = lane >> 4, l16 = lane & 15;

  float* sb = stats + (size_t)b * 32;  // 128B/batch slot
  unsigned* cntp = (unsigned*)sb + 2;
  unsigned* hmp = (unsigned*)sb + 4;
  unsigned* ump = (unsigned*)sb + 6;

  float2* w4 = (float2*)(smem + 8448); // tails after 64*132-short norm buffer
  float* mr = (float*)(smem + 8464);

  // ---------- phase A: partial stats (own s-tile = rows 64mt..64mt+63) ------
  const float4* xb = (const float4*)(x + ((size_t)b * S_ + mt * 64) * D_);
  {
    float s = 0.f, q = 0.f;
#pragma unroll
    for (int i = 0; i < 8; ++i) {
      float4 v = xb[i * 256 + t];
      s += v.x + v.y + v.z + v.w;
      q += v.x * v.x + v.y * v.y + v.z * v.z + v.w * v.w;
    }
#pragma unroll
    for (int o = 32; o > 0; o >>= 1) {
      s += __shfl_down(s, o, 64);
      q += __shfl_down(q, o, 64);
    }
    if (lane == 0) w4[wave] = make_float2(s, q);
  }
  __syncthreads();
  if (t == 0) {
    float ss = 0.f, qq = 0.f;
#pragma unroll
    for (int i = 0; i < 4; ++i) { ss += w4[i].x; qq += w4[i].y; }
    float o1 = __hip_atomic_fetch_add(sb + 0, ss, __ATOMIC_RELAXED,
                                      __HIP_MEMORY_SCOPE_AGENT);
    float o2 = __hip_atomic_fetch_add(sb + 1, qq, __ATOMIC_RELAXED,
                                      __HIP_MEMORY_SCOPE_AGENT);
    asm volatile("" ::"v"(o1), "v"(o2));  // adds complete before cnt bump
    __hip_atomic_fetch_add(cntp, 1u, __ATOMIC_RELAXED,
                           __HIP_MEMORY_SCOPE_AGENT);
    int guard = 0;
    while (__hip_atomic_load(cntp, __ATOMIC_RELAXED,
                             __HIP_MEMORY_SCOPE_AGENT) < 16u) {
      __builtin_amdgcn_s_sleep(1);
      if (++guard > 2000000) break;
    }
    float s1 = __hip_atomic_load(sb + 0, __ATOMIC_RELAXED,
                                 __HIP_MEMORY_SCOPE_AGENT);
    float s2 = __hip_atomic_load(sb + 1, __ATOMIC_RELAXED,
                                 __HIP_MEMORY_SCOPE_AGENT);
    const float inv = 1.0f / (S_ * D_);
    const float mu = s1 * inv;
    mr[0] = mu;
    mr[1] = rsqrtf(s2 * inv - mu * mu + 1e-5f);
  }
  __syncthreads();
  const float mu = mr[0];
  const float rs = mr[1];

  // ---------- normalize (x-tile L1/L2-hot) + LDS [s][d+4pad] transpose ------
  {
    unsigned short* lds = smem;
    const float4* wb = (const float4*)(ln_w + (size_t)(mt * 64) * D_);
    const float4* bv4 = (const float4*)(ln_b + (size_t)(mt * 64) * D_);
#pragma unroll
    for (int r = 0; r < 8; ++r) {
      const int f = r * 256 + t;
      const int srow = f >> 5;
      const int c4 = f & 31;
      float4 xv = xb[f];
      float4 wv = wb[f];
      float4 bvv = bv4[f];
      ushort4 o;
      o.x = f2bf((xv.x - mu) * rs * wv.x + bvv.x);
      o.y = f2bf((xv.y - mu) * rs * wv.y + bvv.y);
      o.z = f2bf((xv.z - mu) * rs * wv.z + bvv.z);
      o.w = f2bf((xv.w - mu) * rs * wv.w + bvv.w);
      *(ushort4*)(lds + srow * 132 + c4 * 4) = o;
    }
    __syncthreads();
    unsigned short* outp = hTf + (size_t)b * (D_ * S_);
    const int cg0 = mt * 2;
#pragma unroll
    for (int ff = 0; ff < 4; ++ff) {
      const int f = wave * 4 + ff;     // 16 fragments per block
      const int p = f >> 1, cl = f & 1;
      const int d = p * 16 + l16;
      const int sbase = cl * 32 + quad * 8;
      bf16x8 v;
#pragma unroll
      for (int jj = 0; jj < 8; ++jj)
        v[jj] = (short)lds[(sbase + jj) * 132 + d];
      store16_dev(outp + ((size_t)p * 32 + cg0 + cl) * 512 + lane * 8, v);
    }
  }
  publish_bit(hmp, 1u << mt);

  // ---------- gemm1: u = hardswish(W1c @ h) ---------------------------------
  gemm_phase<true>(smem, b, mt, hmp, W1f, hTf, uTf, nullptr, nullptr);
  publish_bit(ump, 1u << mt);

  // ---------- gemm2: out = x + W2c @ u --------------------------------------
  gemm_phase<false>(smem, b, mt, ump, W2f, uTf, nullptr, x, out);
}

extern "C" void kernel_launch(void* const* d_in, const int* in_sizes, int n_in,
                              void* d_out, int out_size, void* d_ws, size_t ws_size,
                              hipStream_t stream) {
  const float* x = (const float*)d_in[0];
  const float* ln_w = (const float*)d_in[1];
  const float* ln_b = (const float*)d_in[2];
  const float* W1 = (const float*)d_in[3];
  const float* W2 = (const float*)d_in[4];
  float* out = (float*)d_out;

  char* ws = (char*)d_ws;
  float* stats = (float*)ws;                                 // 8 KiB (64x128B)
  unsigned short* W1f = (unsigned short*)(ws + 16384);       // 2 MiB
  unsigned short* W2f = W1f + (size_t)S_ * S_;               // 2 MiB
  unsigned short* hTf = W2f + (size_t)S_ * S_;               // 16 MiB
  unsigned short* uTf = hTf + (size_t)NB * D_ * S_;          // 16 MiB

  wpack_kernel<<<512, 256, 0, stream>>>(W1, W2, W1f, W2f, (unsigned*)stats);
  mega_kernel<<<1024, 256, 0, stream>>>(x, ln_w, ln_b, W1f, W2f, stats,
                                        hTf, uTf, out);
}